// Round 5
// baseline (38801.685 us; speedup 1.0000x reference)
//
#include <hip/hip_runtime.h>
#include <math.h>

#define SQ 4096
#define HD 512
#define HHD 256
#define TS 8   // sequence rows per block in the parallel GEMMs

// LDS-only barrier: syncs the workgroup WITHOUT draining vmcnt, so global
// publish stores / gx prefetches stay in flight across it. (Compiler's
// __syncthreads inserts s_waitcnt vmcnt(0) -> ~1us store-ack wait per step.)
#define BAR_LDS() asm volatile("s_waitcnt lgkmcnt(0)\n\ts_barrier" ::: "memory")

// ---------------- Kernel A: x = concat(inputs[0], note_emb[ids], chunk_emb[ids]) @ W_comb + b_comb
__global__ __launch_bounds__(512) void kA(const float* __restrict__ inputs,
                                          const int* __restrict__ nid,
                                          const int* __restrict__ cid,
                                          const float* __restrict__ note_emb,
                                          const float* __restrict__ chunk_emb,
                                          const float* __restrict__ Wc,
                                          const float* __restrict__ bc,
                                          float* __restrict__ xln) {
  __shared__ float xcat[TS][1536];
  const int t = threadIdx.x;          // 0..511
  const int s0 = blockIdx.x * TS;
  for (int si = 0; si < TS; ++si) {
    const int s = s0 + si;            // batch 0 only
    xcat[si][t]        = inputs[s * HD + t];
    xcat[si][512 + t]  = note_emb[nid[s] * HD + t];
    xcat[si][1024 + t] = chunk_emb[cid[s] * HD + t];
  }
  __syncthreads();
  float acc[TS];
  const float bcv = bc[t];
#pragma unroll
  for (int si = 0; si < TS; ++si) acc[si] = bcv;
  for (int r = 0; r < 1536; r += 4) {
    const float w0 = Wc[(r + 0) * HD + t];
    const float w1 = Wc[(r + 1) * HD + t];
    const float w2 = Wc[(r + 2) * HD + t];
    const float w3 = Wc[(r + 3) * HD + t];
#pragma unroll
    for (int si = 0; si < TS; ++si) {
      const float4 xv = *reinterpret_cast<const float4*>(&xcat[si][r]);
      acc[si] = fmaf(xv.x, w0, acc[si]);
      acc[si] = fmaf(xv.y, w1, acc[si]);
      acc[si] = fmaf(xv.z, w2, acc[si]);
      acc[si] = fmaf(xv.w, w3, acc[si]);
    }
  }
  for (int si = 0; si < TS; ++si) xln[(s0 + si) * HD + t] = acc[si];
}

// ---------------- Kernel B: in-place LayerNorm over H=512 per row
__global__ __launch_bounds__(256) void kB(float* __restrict__ xln,
                                          const float* __restrict__ g,
                                          const float* __restrict__ b) {
  __shared__ float red[4];
  __shared__ float mu_s, rs_s;
  const int s = blockIdx.x;
  const int t = threadIdx.x;          // 0..255
  const int wave = t >> 6, lane = t & 63;
  float v0 = xln[s * HD + t];
  float v1 = xln[s * HD + t + 256];
  float sum = v0 + v1;
#pragma unroll
  for (int o = 32; o >= 1; o >>= 1) sum += __shfl_down(sum, o, 64);
  if (lane == 0) red[wave] = sum;
  __syncthreads();
  if (t == 0) mu_s = (red[0] + red[1] + red[2] + red[3]) * (1.0f / 512.0f);
  __syncthreads();
  const float mu = mu_s;
  const float d0 = v0 - mu, d1 = v1 - mu;
  float vs = d0 * d0 + d1 * d1;
#pragma unroll
  for (int o = 32; o >= 1; o >>= 1) vs += __shfl_down(vs, o, 64);
  if (lane == 0) red[wave] = vs;
  __syncthreads();
  if (t == 0) rs_s = rsqrtf((red[0] + red[1] + red[2] + red[3]) * (1.0f / 512.0f) + 1e-12f);
  __syncthreads();
  const float rs = rs_s;
  xln[s * HD + t]       = d0 * rs * g[t] + b[t];
  xln[s * HD + t + 256] = d1 * rs * g[t + 256] + b[t + 256];
}

// ---------------- Kernel C: gx[dir][s][k*256+j] = x[s_eff] @ Wx[dir][k][:,j] + bg[dir][k][j]
__global__ __launch_bounds__(512) void kC(const float* __restrict__ xln,
                                          const float* __restrict__ Wx,
                                          const float* __restrict__ bg,
                                          float* __restrict__ gx) {
  __shared__ float xs[TS][HD];
  const int t = threadIdx.x;          // 0..511
  const int dir = blockIdx.y;
  const int s0 = blockIdx.x * TS;
  for (int si = 0; si < TS; ++si) {
    const int sx = dir ? (SQ - 1 - (s0 + si)) : (s0 + si);
    xs[si][t] = xln[sx * HD + t];
  }
  __syncthreads();
  const int k1 = t >> 8, j = t & 255;
  const int k2 = k1 + 2;
  const float* w1 = Wx + (size_t)(dir * 4 + k1) * HD * HHD + j;
  const float* w2 = Wx + (size_t)(dir * 4 + k2) * HD * HHD + j;
  float acc1[TS], acc2[TS];
  const float b1 = bg[(dir * 4 + k1) * HHD + j];
  const float b2 = bg[(dir * 4 + k2) * HHD + j];
#pragma unroll
  for (int si = 0; si < TS; ++si) { acc1[si] = b1; acc2[si] = b2; }
  for (int d = 0; d < HD; d += 4) {
    const float w1a = w1[(d + 0) * HHD], w1b = w1[(d + 1) * HHD];
    const float w1c = w1[(d + 2) * HHD], w1d = w1[(d + 3) * HHD];
    const float w2a = w2[(d + 0) * HHD], w2b = w2[(d + 1) * HHD];
    const float w2c = w2[(d + 2) * HHD], w2d = w2[(d + 3) * HHD];
#pragma unroll
    for (int si = 0; si < TS; ++si) {
      const float4 xv = *reinterpret_cast<const float4*>(&xs[si][d]);
      acc1[si] = fmaf(xv.x, w1a, acc1[si]);
      acc1[si] = fmaf(xv.y, w1b, acc1[si]);
      acc1[si] = fmaf(xv.z, w1c, acc1[si]);
      acc1[si] = fmaf(xv.w, w1d, acc1[si]);
      acc2[si] = fmaf(xv.x, w2a, acc2[si]);
      acc2[si] = fmaf(xv.y, w2b, acc2[si]);
      acc2[si] = fmaf(xv.z, w2c, acc2[si]);
      acc2[si] = fmaf(xv.w, w2d, acc2[si]);
    }
  }
  for (int si = 0; si < TS; ++si) {
    float* row = gx + ((size_t)(dir * SQ + s0 + si)) * 1024;
    row[t]       = acc1[si];
    row[t + 512] = acc2[si];
  }
}

__device__ __forceinline__ float tanh_fast(float x) {
  const float ax = fabsf(x);
  const float e  = __expf(-2.0f * ax);
  const float t  = __fdividef(1.0f - e, 1.0f + e);
  return copysignf(t, x);
}

// ---------------- Kernel R: sequential TLSTM recurrence.
// 26 blocks; only blockIdx%8 < 2 participate: dir = blockIdx%8, wg = blockIdx>>3.
// With round-robin block->XCD dispatch this co-locates each direction's 4 WGs on
// one XCD (perf heuristic only). Each WG owns 64 hidden cols, weights in VGPRs.
// Split-K: wave w computes h-slice-w partials for all 64 owned cols (32 uniform
// b128 LDS reads/wave/step). Wave wg (local slice) does epilogue+publish; waves
// w!=wg each poll exactly the sibling chunk (WG w) their next dot needs.
// Exchange: 8B relaxed agent atomics, tag(s+1)<<32 | fp32 bits, parity dbuf.
// In-loop barriers are LDS-only (BAR_LDS) so publish stores & gx prefetch stay
// in flight — no vmcnt(0) drain per step. gx prefetch is issued BEFORE the
// publish stores each step, so vmcnt FIFO never makes gx-use wait on store-acks.
__global__ __launch_bounds__(256, 1) void kR(const float* __restrict__ gx,
                                             const float* __restrict__ Wh,
                                             const float* __restrict__ Wd,
                                             const float* __restrict__ bd,
                                             const float* __restrict__ times,
                                             unsigned long long* __restrict__ comm,
                                             float* __restrict__ hfin) {
  const int slot = blockIdx.x & 7;
  if (slot >= 2) return;
  const int dir = slot;
  const int wg  = blockIdx.x >> 3;    // 0..3
  const int t   = threadIdx.x;        // 0..255
  const int w   = t >> 6;             // wave id == h/c slice it processes
  const int u   = t & 63;
  const int c0  = wg * 64;
  const int j   = c0 + u;             // owned global column

  unsigned long long* mybase = comm + (size_t)((dir * 4 + wg) * 2) * 128;
  const unsigned long long* sibbase = comm + (size_t)((dir * 4 + w) * 2) * 128;

  // Persistent weights: Wh rows [64w,64w+64) x 4 gates x col j; Wd rows [64w,..) x col j.
  float wh[256];                      // wh[k*64+i]
#pragma unroll
  for (int k = 0; k < 4; ++k)
    for (int i = 0; i < 64; ++i)
      wh[k * 64 + i] = Wh[((size_t)(dir * 4 + k) * HHD + (w * 64 + i)) * HHD + j];
  float wd[64];
#pragma unroll
  for (int i = 0; i < 64; ++i)
    wd[i] = Wd[(size_t)dir * HHD * HHD + (size_t)(w * 64 + i) * HHD + j];

  __shared__ float h_all[HHD];
  __shared__ float c_all[HHD];
  __shared__ float pg[4][4][64];      // [gate][slice][col]
  __shared__ float pd[4][64];         // [slice][col]
  __shared__ float T_pre[SQ];

  for (int s = t; s < SQ; s += 256) {
    const int sidx = dir ? ((s == 0) ? 0 : (SQ - s)) : s;
    T_pre[s] = 1.0f / logf(times[sidx] + 2.7182818284590452354f);
  }
  h_all[t] = 0.0f;
  c_all[t] = 0.0f;
  __syncthreads();                     // prologue: full barrier is fine (once)

  const bool owner = (w == wg);
  const float bdv = owner ? bd[dir * HHD + j] : 0.0f;
  const float* gxd = gx + (size_t)dir * SQ * 1024 + j;   // + k*256 per gate

  // gx prefetch registers (owner wave only): gates 0..3 at column j.
  float g0 = 0, g1 = 0, g2 = 0, g3 = 0;
  if (owner) {
    g0 = gxd[0];
    g1 = gxd[256];
    g2 = gxd[512];
    g3 = gxd[768];
  }

  for (int s = 0; s < SQ; ++s) {
    // Owner: issue next step's gx loads FIRST (older than publish stores).
    float n0 = 0, n1 = 0, n2 = 0, n3 = 0;
    if (owner && s + 1 < SQ) {
      const float* row = gxd + (size_t)(s + 1) * 1024;
      n0 = row[0];
      n1 = row[256];
      n2 = row[512];
      n3 = row[768];
    }
    // Split-K dot: slice w of h (and c) against resident weights.
    float a0 = 0, a1 = 0, a2 = 0, a3 = 0, adp = 0;
    const float4* h4 = reinterpret_cast<const float4*>(h_all) + w * 16;
    const float4* c4 = reinterpret_cast<const float4*>(c_all) + w * 16;
#pragma unroll
    for (int ii = 0; ii < 16; ++ii) {
      const float4 hv = h4[ii];
      const float4 cv = c4[ii];
#pragma unroll
      for (int e = 0; e < 4; ++e) {
        const int i = ii * 4 + e;
        const float hx = (&hv.x)[e];
        a0  = fmaf(wh[i],       hx, a0);
        a1  = fmaf(wh[64 + i],  hx, a1);
        a2  = fmaf(wh[128 + i], hx, a2);
        a3  = fmaf(wh[192 + i], hx, a3);
        adp = fmaf(wd[i], (&cv.x)[e], adp);
      }
    }
    pg[0][w][u] = a0;
    pg[1][w][u] = a1;
    pg[2][w][u] = a2;
    pg[3][w][u] = a3;
    pd[w][u]    = adp;
    BAR_LDS();                                          // B1
    if (owner) {
      const float s0 = pg[0][0][u] + pg[0][1][u] + pg[0][2][u] + pg[0][3][u];
      const float s1 = pg[1][0][u] + pg[1][1][u] + pg[1][2][u] + pg[1][3][u];
      const float s2 = pg[2][0][u] + pg[2][1][u] + pg[2][2][u] + pg[2][3][u];
      const float s3 = pg[3][0][u] + pg[3][1][u] + pg[3][2][u] + pg[3][3][u];
      const float sd = pd[0][u] + pd[1][u] + pd[2][u] + pd[3][u];
      const float iv  = __fdividef(1.0f, 1.0f + __expf(-(s0 + g0)));
      const float fv  = __fdividef(1.0f, 1.0f + __expf(-(s1 + g1)));
      const float ov  = __fdividef(1.0f, 1.0f + __expf(-(s2 + g2)));
      const float cgv = __fdividef(1.0f, 1.0f + __expf(-(s3 + g3)));
      const float c_st = tanh_fast(sd + bdv);
      const float T = T_pre[s];
      const float c_adj = c_all[j] + (T - 1.0f) * c_st;
      const float ct = fv * c_adj + iv * cgv;
      const float hn = ov * tanh_fast(ct);
      c_all[j] = ct;
      h_all[j] = hn;
      unsigned long long* chunk = mybase + (size_t)(s & 1) * 128;
      const unsigned long long tg = ((unsigned long long)(unsigned)(s + 1)) << 32;
      __hip_atomic_store(chunk + u,      tg | (unsigned long long)__float_as_uint(hn),
                         __ATOMIC_RELAXED, __HIP_MEMORY_SCOPE_AGENT);
      __hip_atomic_store(chunk + 64 + u, tg | (unsigned long long)__float_as_uint(ct),
                         __ATOMIC_RELAXED, __HIP_MEMORY_SCOPE_AGENT);
      // no ack wait: BAR_LDS doesn't drain vmcnt
    } else {
      // wave w polls WG w's chunk — exactly the slice its next dot consumes
      const unsigned long long* chunk = sibbase + (size_t)(s & 1) * 128;
      const unsigned tag = (unsigned)(s + 1);
      unsigned long long hw = 0, cw = 0;
      bool okh = false, okc = false;
      do {
        if (!okh) {
          hw = __hip_atomic_load(chunk + u, __ATOMIC_RELAXED, __HIP_MEMORY_SCOPE_AGENT);
          okh = ((unsigned)(hw >> 32) == tag);
        }
        if (!okc) {
          cw = __hip_atomic_load(chunk + 64 + u, __ATOMIC_RELAXED, __HIP_MEMORY_SCOPE_AGENT);
          okc = ((unsigned)(cw >> 32) == tag);
        }
      } while (!(okh && okc));
      h_all[w * 64 + u] = __uint_as_float((unsigned)hw);
      c_all[w * 64 + u] = __uint_as_float((unsigned)cw);
    }
    BAR_LDS();                                          // B2
    g0 = n0; g1 = n1; g2 = n2; g3 = n3;
  }
  if (owner) hfin[dir * HHD + j] = h_all[j];
}

// ---------------- Kernel D: logits = concat(hf,hb) @ W_cls + b_cls -> sigmoid -> out
__global__ __launch_bounds__(512) void kD(const float* __restrict__ hfin,
                                          const float* __restrict__ Wcls,
                                          const float* __restrict__ bcls,
                                          float* __restrict__ out) {
  __shared__ float red[8];
  const int t = threadIdx.x;          // 0..511
  float v = hfin[t] * Wcls[t];
#pragma unroll
  for (int o = 32; o >= 1; o >>= 1) v += __shfl_down(v, o, 64);
  if ((t & 63) == 0) red[t >> 6] = v;
  __syncthreads();
  if (t == 0) {
    float l = red[0] + red[1] + red[2] + red[3] + red[4] + red[5] + red[6] + red[7] + bcls[0];
    if (isnan(l) || isinf(l)) l = 0.0f;
    float p = 1.0f / (1.0f + expf(-l));
    if (isnan(p) || isinf(p)) p = 0.0f;
    out[0] = p;
  }
}

extern "C" void kernel_launch(void* const* d_in, const int* in_sizes, int n_in,
                              void* d_out, int out_size, void* d_ws, size_t ws_size,
                              hipStream_t stream) {
  const float* inputs    = (const float*)d_in[0];
  const float* times     = (const float*)d_in[1];
  const int*   nid       = (const int*)d_in[2];
  const int*   cid       = (const int*)d_in[3];
  const float* note_emb  = (const float*)d_in[4];
  const float* chunk_emb = (const float*)d_in[5];
  const float* W_comb    = (const float*)d_in[6];
  const float* b_comb    = (const float*)d_in[7];
  const float* ln_g      = (const float*)d_in[8];
  const float* ln_b      = (const float*)d_in[9];
  const float* Wx        = (const float*)d_in[10];
  const float* Wh        = (const float*)d_in[11];
  const float* bg        = (const float*)d_in[12];
  const float* Wd        = (const float*)d_in[13];
  const float* bd        = (const float*)d_in[14];
  const float* W_cls     = (const float*)d_in[15];
  const float* b_cls     = (const float*)d_in[16];

  float* ws   = (float*)d_ws;
  float* xln  = ws;                              // 4096*512    floats
  float* gx   = ws + (size_t)SQ * HD;            // 2*4096*1024 floats
  float* hfin = gx + (size_t)2 * SQ * 1024;      // 512 floats
  unsigned long long* comm = (unsigned long long*)(hfin + 512);  // 8*2*128 u64

  kA<<<SQ / TS, 512, 0, stream>>>(inputs, nid, cid, note_emb, chunk_emb, W_comb, b_comb, xln);
  kB<<<SQ, 256, 0, stream>>>(xln, ln_g, ln_b);
  kC<<<dim3(SQ / TS, 2), 512, 0, stream>>>(xln, Wx, bg, gx);
  kR<<<26, 256, 0, stream>>>(gx, Wh, Wd, bd, times, comm, hfin);
  kD<<<1, 512, 0, stream>>>(hfin, W_cls, b_cls, (float*)d_out);
}

// Round 6
// 22365.323 us; speedup vs baseline: 1.7349x; 1.7349x over previous
//
#include <hip/hip_runtime.h>
#include <math.h>

#define SQ 4096
#define HD 512
#define HHD 256
#define TS 8   // sequence rows per block in the parallel GEMMs

// LDS-only barrier: syncs the workgroup WITHOUT draining vmcnt, so global
// publish stores / gx prefetches stay in flight across it. (__syncthreads
// emits s_waitcnt vmcnt(0) before s_barrier -> per-step store-ack drain.)
#define BAR_LDS() asm volatile("s_waitcnt lgkmcnt(0)\n\ts_barrier" ::: "memory")

// ---------------- Kernel A: x = concat(inputs[0], note_emb[ids], chunk_emb[ids]) @ W_comb + b_comb
__global__ __launch_bounds__(512) void kA(const float* __restrict__ inputs,
                                          const int* __restrict__ nid,
                                          const int* __restrict__ cid,
                                          const float* __restrict__ note_emb,
                                          const float* __restrict__ chunk_emb,
                                          const float* __restrict__ Wc,
                                          const float* __restrict__ bc,
                                          float* __restrict__ xln) {
  __shared__ float xcat[TS][1536];
  const int t = threadIdx.x;          // 0..511
  const int s0 = blockIdx.x * TS;
  for (int si = 0; si < TS; ++si) {
    const int s = s0 + si;            // batch 0 only
    xcat[si][t]        = inputs[s * HD + t];
    xcat[si][512 + t]  = note_emb[nid[s] * HD + t];
    xcat[si][1024 + t] = chunk_emb[cid[s] * HD + t];
  }
  __syncthreads();
  float acc[TS];
  const float bcv = bc[t];
#pragma unroll
  for (int si = 0; si < TS; ++si) acc[si] = bcv;
  for (int r = 0; r < 1536; r += 4) {
    const float w0 = Wc[(r + 0) * HD + t];
    const float w1 = Wc[(r + 1) * HD + t];
    const float w2 = Wc[(r + 2) * HD + t];
    const float w3 = Wc[(r + 3) * HD + t];
#pragma unroll
    for (int si = 0; si < TS; ++si) {
      const float4 xv = *reinterpret_cast<const float4*>(&xcat[si][r]);
      acc[si] = fmaf(xv.x, w0, acc[si]);
      acc[si] = fmaf(xv.y, w1, acc[si]);
      acc[si] = fmaf(xv.z, w2, acc[si]);
      acc[si] = fmaf(xv.w, w3, acc[si]);
    }
  }
  for (int si = 0; si < TS; ++si) xln[(s0 + si) * HD + t] = acc[si];
}

// ---------------- Kernel B: in-place LayerNorm over H=512 per row
__global__ __launch_bounds__(256) void kB(float* __restrict__ xln,
                                          const float* __restrict__ g,
                                          const float* __restrict__ b) {
  __shared__ float red[4];
  __shared__ float mu_s, rs_s;
  const int s = blockIdx.x;
  const int t = threadIdx.x;          // 0..255
  const int wave = t >> 6, lane = t & 63;
  float v0 = xln[s * HD + t];
  float v1 = xln[s * HD + t + 256];
  float sum = v0 + v1;
#pragma unroll
  for (int o = 32; o >= 1; o >>= 1) sum += __shfl_down(sum, o, 64);
  if (lane == 0) red[wave] = sum;
  __syncthreads();
  if (t == 0) mu_s = (red[0] + red[1] + red[2] + red[3]) * (1.0f / 512.0f);
  __syncthreads();
  const float mu = mu_s;
  const float d0 = v0 - mu, d1 = v1 - mu;
  float vs = d0 * d0 + d1 * d1;
#pragma unroll
  for (int o = 32; o >= 1; o >>= 1) vs += __shfl_down(vs, o, 64);
  if (lane == 0) red[wave] = vs;
  __syncthreads();
  if (t == 0) rs_s = rsqrtf((red[0] + red[1] + red[2] + red[3]) * (1.0f / 512.0f) + 1e-12f);
  __syncthreads();
  const float rs = rs_s;
  xln[s * HD + t]       = d0 * rs * g[t] + b[t];
  xln[s * HD + t + 256] = d1 * rs * g[t + 256] + b[t + 256];
}

// ---------------- Kernel C: gx[dir][s][k*256+j] = x[s_eff] @ Wx[dir][k][:,j] + bg[dir][k][j]
__global__ __launch_bounds__(512) void kC(const float* __restrict__ xln,
                                          const float* __restrict__ Wx,
                                          const float* __restrict__ bg,
                                          float* __restrict__ gx) {
  __shared__ float xs[TS][HD];
  const int t = threadIdx.x;          // 0..511
  const int dir = blockIdx.y;
  const int s0 = blockIdx.x * TS;
  for (int si = 0; si < TS; ++si) {
    const int sx = dir ? (SQ - 1 - (s0 + si)) : (s0 + si);
    xs[si][t] = xln[sx * HD + t];
  }
  __syncthreads();
  const int k1 = t >> 8, j = t & 255;
  const int k2 = k1 + 2;
  const float* w1 = Wx + (size_t)(dir * 4 + k1) * HD * HHD + j;
  const float* w2 = Wx + (size_t)(dir * 4 + k2) * HD * HHD + j;
  float acc1[TS], acc2[TS];
  const float b1 = bg[(dir * 4 + k1) * HHD + j];
  const float b2 = bg[(dir * 4 + k2) * HHD + j];
#pragma unroll
  for (int si = 0; si < TS; ++si) { acc1[si] = b1; acc2[si] = b2; }
  for (int d = 0; d < HD; d += 4) {
    const float w1a = w1[(d + 0) * HHD], w1b = w1[(d + 1) * HHD];
    const float w1c = w1[(d + 2) * HHD], w1d = w1[(d + 3) * HHD];
    const float w2a = w2[(d + 0) * HHD], w2b = w2[(d + 1) * HHD];
    const float w2c = w2[(d + 2) * HHD], w2d = w2[(d + 3) * HHD];
#pragma unroll
    for (int si = 0; si < TS; ++si) {
      const float4 xv = *reinterpret_cast<const float4*>(&xs[si][d]);
      acc1[si] = fmaf(xv.x, w1a, acc1[si]);
      acc1[si] = fmaf(xv.y, w1b, acc1[si]);
      acc1[si] = fmaf(xv.z, w1c, acc1[si]);
      acc1[si] = fmaf(xv.w, w1d, acc1[si]);
      acc2[si] = fmaf(xv.x, w2a, acc2[si]);
      acc2[si] = fmaf(xv.y, w2b, acc2[si]);
      acc2[si] = fmaf(xv.z, w2c, acc2[si]);
      acc2[si] = fmaf(xv.w, w2d, acc2[si]);
    }
  }
  for (int si = 0; si < TS; ++si) {
    float* row = gx + ((size_t)(dir * SQ + s0 + si)) * 1024;
    row[t]       = acc1[si];
    row[t + 512] = acc2[si];
  }
}

__device__ __forceinline__ float tanh_fast(float x) {
  const float ax = fabsf(x);
  const float e  = __expf(-2.0f * ax);
  const float t  = __fdividef(1.0f - e, 1.0f + e);
  return copysignf(t, x);
}

// ---------------- Kernel R: sequential TLSTM recurrence.
// 26 blocks; only blockIdx&7 < 2 work: dir = blockIdx&7, wg = blockIdx>>3.
// (Round-robin block->XCD dispatch co-locates each direction's 4 WGs on one
// XCD — perf heuristic only.) Each WG owns 64 hidden cols; wave k computes the
// full 256-dot for gate k of those cols. Weights persistent in VGPRs — weight
// load loops MUST stay single-level + fully unrolled (r5's nested loop rolled
// -> dynamic index -> scratch spill, VGPR 56, 38 ms. Verify VGPR_Count ~256).
// Exchange: ONE 8-byte relaxed agent atomic per value (tag<<32|fp32), parity
// double-buffer (2-step overwrite window protocol-safe). In-loop barriers are
// LDS-only (BAR_LDS) so publish stores & gx prefetch stay in flight — the
// compiler's vmcnt(0)-before-s_barrier was draining a cross-XCD store ack
// every step in r3/r4.
__global__ __launch_bounds__(256, 1) void kR(const float* __restrict__ gx,
                                             const float* __restrict__ Wh,
                                             const float* __restrict__ Wd,
                                             const float* __restrict__ bd,
                                             const float* __restrict__ times,
                                             unsigned long long* __restrict__ comm,
                                             float* __restrict__ hfin) {
  const int slot = blockIdx.x & 7;
  if (slot >= 2) return;
  const int dir = slot;
  const int wg  = blockIdx.x >> 3;    // 0..3
  const int t   = threadIdx.x;        // 0..255
  const int k   = t >> 6;             // gate index == wave id
  const int u   = t & 63;
  const int c0  = wg * 64;
  const int j   = c0 + u;             // owned global column

  // chunk layout: comm[((dir*4+w)*2 + parity)*128 + {u: h, 64+u: c}]
  unsigned long long* mybase = comm + (size_t)((dir * 4 + wg) * 2) * 128;
  const int sib = (wg + k) & 3;                      // waves 1..3 poll this sibling
  const unsigned long long* sibbase = comm + (size_t)((dir * 4 + sib) * 2) * 128;

  // Persistent weights in registers — single-level fully-unrolled loads.
  float wh[256];
  const float* whp = Wh + ((size_t)(dir * 4 + k) * HHD) * HHD + j;
#pragma unroll
  for (int i = 0; i < 256; ++i) wh[i] = whp[i * HHD];
  float wd[64];
  const float* wdpp = Wd + (size_t)dir * HHD * HHD + (k * 64) * HHD + j;
#pragma unroll
  for (int i = 0; i < 64; ++i) wd[i] = wdpp[i * HHD];

  __shared__ float h_all[HHD];
  __shared__ float c_all[HHD];
  __shared__ float g_lds[4][64];
  __shared__ float wdp_lds[4][64];
  __shared__ float T_pre[SQ];          // 16 KB: precomputed 1/log(t+e)

  for (int s = t; s < SQ; s += 256) {
    const int sidx = dir ? ((s == 0) ? 0 : (SQ - s)) : s;
    T_pre[s] = 1.0f / logf(times[sidx] + 2.7182818284590452354f);
  }
  h_all[t] = 0.0f;
  c_all[t] = 0.0f;
  __syncthreads();                     // prologue only

  const float bdv = (k == 0) ? bd[dir * HHD + c0 + u] : 0.0f;
  const float* gxcol = gx + (size_t)dir * SQ * 1024 + (size_t)(k * 256 + j);

  float gxv = gxcol[0];
  for (int s = 0; s < SQ; ++s) {
    const float gx_next = (s + 1 < SQ) ? gxcol[(size_t)(s + 1) * 1024] : 0.0f;  // prefetch
    // gate preactivation: h_all @ Wh[:, j] — 4 independent accumulator chains
    float ax = 0.0f, ay = 0.0f, az = 0.0f, aw = 0.0f;
    const float4* h4 = reinterpret_cast<const float4*>(h_all);
#pragma unroll
    for (int ii = 0; ii < 64; ++ii) {
      const float4 hv = h4[ii];
      ax = fmaf(wh[4 * ii + 0], hv.x, ax);
      ay = fmaf(wh[4 * ii + 1], hv.y, ay);
      az = fmaf(wh[4 * ii + 2], hv.z, az);
      aw = fmaf(wh[4 * ii + 3], hv.w, aw);
    }
    const float acc = (ax + ay) + (az + aw);
    // partial of c_all @ Wd[:, j]: rows [64k, 64k+64)
    float bx = 0.0f, by = 0.0f, bz = 0.0f, bw = 0.0f;
    const float4* c4 = reinterpret_cast<const float4*>(c_all) + k * 16;
#pragma unroll
    for (int ii = 0; ii < 16; ++ii) {
      const float4 cv = c4[ii];
      bx = fmaf(wd[4 * ii + 0], cv.x, bx);
      by = fmaf(wd[4 * ii + 1], cv.y, by);
      bz = fmaf(wd[4 * ii + 2], cv.z, bz);
      bw = fmaf(wd[4 * ii + 3], cv.w, bw);
    }
    g_lds[k][u]   = __fdividef(1.0f, 1.0f + __expf(-(acc + gxv)));
    wdp_lds[k][u] = (bx + by) + (bz + bw);
    BAR_LDS();                                         // B1 (no vmcnt drain)
    if (k == 0) {
      // epilogue + publish (wave 0; wave-uniform branch)
      const float wsum = wdp_lds[0][u] + wdp_lds[1][u] + wdp_lds[2][u] + wdp_lds[3][u];
      const float c_st = tanh_fast(wsum + bdv);
      const float T = T_pre[s];
      const float c_adj = c_all[j] + (T - 1.0f) * c_st;
      const float iv = g_lds[0][u], fv = g_lds[1][u], ov = g_lds[2][u], cgv = g_lds[3][u];
      const float ct = fv * c_adj + iv * cgv;
      const float hn = ov * tanh_fast(ct);
      c_all[j] = ct;
      h_all[j] = hn;
      unsigned long long* chunk = mybase + (size_t)(s & 1) * 128;
      const unsigned long long tg = ((unsigned long long)(unsigned)(s + 1)) << 32;
      __hip_atomic_store(chunk + u,      tg | (unsigned long long)__float_as_uint(hn),
                         __ATOMIC_RELAXED, __HIP_MEMORY_SCOPE_AGENT);
      __hip_atomic_store(chunk + 64 + u, tg | (unsigned long long)__float_as_uint(ct),
                         __ATOMIC_RELAXED, __HIP_MEMORY_SCOPE_AGENT);
      // fire-and-forget: BAR_LDS won't wait for the ack
    } else {
      // waves 1..3: poll sibling chunk; tag match == data in hand
      const unsigned long long* chunk = sibbase + (size_t)(s & 1) * 128;
      const unsigned tag = (unsigned)(s + 1);
      unsigned long long hw = 0, cw = 0;
      bool okh = false, okc = false;
      do {
        if (!okh) {
          hw = __hip_atomic_load(chunk + u, __ATOMIC_RELAXED, __HIP_MEMORY_SCOPE_AGENT);
          okh = ((unsigned)(hw >> 32) == tag);
        }
        if (!okc) {
          cw = __hip_atomic_load(chunk + 64 + u, __ATOMIC_RELAXED, __HIP_MEMORY_SCOPE_AGENT);
          okc = ((unsigned)(cw >> 32) == tag);
        }
      } while (!(okh && okc));
      h_all[sib * 64 + u] = __uint_as_float((unsigned)hw);
      c_all[sib * 64 + u] = __uint_as_float((unsigned)cw);
    }
    BAR_LDS();                                         // B2 (no vmcnt drain)
    gxv = gx_next;
  }
  if (k == 0) hfin[dir * HHD + j] = h_all[j];
}

// ---------------- Kernel D: logits = concat(hf,hb) @ W_cls + b_cls -> sigmoid -> out
__global__ __launch_bounds__(512) void kD(const float* __restrict__ hfin,
                                          const float* __restrict__ Wcls,
                                          const float* __restrict__ bcls,
                                          float* __restrict__ out) {
  __shared__ float red[8];
  const int t = threadIdx.x;          // 0..511
  float v = hfin[t] * Wcls[t];
#pragma unroll
  for (int o = 32; o >= 1; o >>= 1) v += __shfl_down(v, o, 64);
  if ((t & 63) == 0) red[t >> 6] = v;
  __syncthreads();
  if (t == 0) {
    float l = red[0] + red[1] + red[2] + red[3] + red[4] + red[5] + red[6] + red[7] + bcls[0];
    if (isnan(l) || isinf(l)) l = 0.0f;
    float p = 1.0f / (1.0f + expf(-l));
    if (isnan(p) || isinf(p)) p = 0.0f;
    out[0] = p;
  }
}

extern "C" void kernel_launch(void* const* d_in, const int* in_sizes, int n_in,
                              void* d_out, int out_size, void* d_ws, size_t ws_size,
                              hipStream_t stream) {
  const float* inputs    = (const float*)d_in[0];
  const float* times     = (const float*)d_in[1];
  const int*   nid       = (const int*)d_in[2];
  const int*   cid       = (const int*)d_in[3];
  const float* note_emb  = (const float*)d_in[4];
  const float* chunk_emb = (const float*)d_in[5];
  const float* W_comb    = (const float*)d_in[6];
  const float* b_comb    = (const float*)d_in[7];
  const float* ln_g      = (const float*)d_in[8];
  const float* ln_b      = (const float*)d_in[9];
  const float* Wx        = (const float*)d_in[10];
  const float* Wh        = (const float*)d_in[11];
  const float* bg        = (const float*)d_in[12];
  const float* Wd        = (const float*)d_in[13];
  const float* bd        = (const float*)d_in[14];
  const float* W_cls     = (const float*)d_in[15];
  const float* b_cls     = (const float*)d_in[16];

  float* ws   = (float*)d_ws;
  float* xln  = ws;                              // 4096*512    floats
  float* gx   = ws + (size_t)SQ * HD;            // 2*4096*1024 floats
  float* hfin = gx + (size_t)2 * SQ * 1024;      // 512 floats
  unsigned long long* comm = (unsigned long long*)(hfin + 512);  // 8*2*128 u64

  kA<<<SQ / TS, 512, 0, stream>>>(inputs, nid, cid, note_emb, chunk_emb, W_comb, b_comb, xln);
  kB<<<SQ, 256, 0, stream>>>(xln, ln_g, ln_b);
  kC<<<dim3(SQ / TS, 2), 512, 0, stream>>>(xln, Wx, bg, gx);
  kR<<<26, 256, 0, stream>>>(gx, Wh, Wd, bd, times, comm, hfin);
  kD<<<1, 512, 0, stream>>>(hfin, W_cls, b_cls, (float*)d_out);
}

// Round 7
// 7517.776 us; speedup vs baseline: 5.1613x; 2.9750x over previous
//
#include <hip/hip_runtime.h>
#include <math.h>

#define SQ 4096
#define HD 512
#define HHD 256
#define TS 8   // sequence rows per block in the parallel GEMMs

// LDS-only barrier: syncs the workgroup WITHOUT draining vmcnt.
#define BAR_LDS() asm volatile("s_waitcnt lgkmcnt(0)\n\ts_barrier" ::: "memory")

typedef _Float16 h2 __attribute__((ext_vector_type(2)));

__device__ __forceinline__ h2 u2h(unsigned v) { union { unsigned u; h2 h; } x; x.u = v; return x.h; }
__device__ __forceinline__ unsigned h2u(h2 v) { union { unsigned u; h2 h; } x; x.h = v; return x.u; }

__device__ __forceinline__ float fdot2f(h2 a, h2 b, float c) {
#if __has_builtin(__builtin_amdgcn_fdot2)
  return __builtin_amdgcn_fdot2(a, b, c, false);
#else
  return fmaf((float)a.x, (float)b.x, fmaf((float)a.y, (float)b.y, c));
#endif
}

// ---------------- Kernel A: x = concat(inputs[0], note_emb[ids], chunk_emb[ids]) @ W_comb + b_comb
__global__ __launch_bounds__(512) void kA(const float* __restrict__ inputs,
                                          const int* __restrict__ nid,
                                          const int* __restrict__ cid,
                                          const float* __restrict__ note_emb,
                                          const float* __restrict__ chunk_emb,
                                          const float* __restrict__ Wc,
                                          const float* __restrict__ bc,
                                          float* __restrict__ xln) {
  __shared__ float xcat[TS][1536];
  const int t = threadIdx.x;          // 0..511
  const int s0 = blockIdx.x * TS;
  for (int si = 0; si < TS; ++si) {
    const int s = s0 + si;            // batch 0 only
    xcat[si][t]        = inputs[s * HD + t];
    xcat[si][512 + t]  = note_emb[nid[s] * HD + t];
    xcat[si][1024 + t] = chunk_emb[cid[s] * HD + t];
  }
  __syncthreads();
  float acc[TS];
  const float bcv = bc[t];
#pragma unroll
  for (int si = 0; si < TS; ++si) acc[si] = bcv;
  for (int r = 0; r < 1536; r += 4) {
    const float w0 = Wc[(r + 0) * HD + t];
    const float w1 = Wc[(r + 1) * HD + t];
    const float w2 = Wc[(r + 2) * HD + t];
    const float w3 = Wc[(r + 3) * HD + t];
#pragma unroll
    for (int si = 0; si < TS; ++si) {
      const float4 xv = *reinterpret_cast<const float4*>(&xcat[si][r]);
      acc[si] = fmaf(xv.x, w0, acc[si]);
      acc[si] = fmaf(xv.y, w1, acc[si]);
      acc[si] = fmaf(xv.z, w2, acc[si]);
      acc[si] = fmaf(xv.w, w3, acc[si]);
    }
  }
  for (int si = 0; si < TS; ++si) xln[(s0 + si) * HD + t] = acc[si];
}

// ---------------- Kernel B: in-place LayerNorm over H=512 per row
__global__ __launch_bounds__(256) void kB(float* __restrict__ xln,
                                          const float* __restrict__ g,
                                          const float* __restrict__ b) {
  __shared__ float red[4];
  __shared__ float mu_s, rs_s;
  const int s = blockIdx.x;
  const int t = threadIdx.x;          // 0..255
  const int wave = t >> 6, lane = t & 63;
  float v0 = xln[s * HD + t];
  float v1 = xln[s * HD + t + 256];
  float sum = v0 + v1;
#pragma unroll
  for (int o = 32; o >= 1; o >>= 1) sum += __shfl_down(sum, o, 64);
  if (lane == 0) red[wave] = sum;
  __syncthreads();
  if (t == 0) mu_s = (red[0] + red[1] + red[2] + red[3]) * (1.0f / 512.0f);
  __syncthreads();
  const float mu = mu_s;
  const float d0 = v0 - mu, d1 = v1 - mu;
  float vs = d0 * d0 + d1 * d1;
#pragma unroll
  for (int o = 32; o >= 1; o >>= 1) vs += __shfl_down(vs, o, 64);
  if (lane == 0) red[wave] = vs;
  __syncthreads();
  if (t == 0) rs_s = rsqrtf((red[0] + red[1] + red[2] + red[3]) * (1.0f / 512.0f) + 1e-12f);
  __syncthreads();
  const float rs = rs_s;
  xln[s * HD + t]       = d0 * rs * g[t] + b[t];
  xln[s * HD + t + 256] = d1 * rs * g[t + 256] + b[t + 256];
}

// ---------------- Kernel C: gx[dir][s][k*256+j] = x[s_eff] @ Wx[dir][k][:,j] + bg[dir][k][j]
__global__ __launch_bounds__(512) void kC(const float* __restrict__ xln,
                                          const float* __restrict__ Wx,
                                          const float* __restrict__ bg,
                                          float* __restrict__ gx) {
  __shared__ float xs[TS][HD];
  const int t = threadIdx.x;          // 0..511
  const int dir = blockIdx.y;
  const int s0 = blockIdx.x * TS;
  for (int si = 0; si < TS; ++si) {
    const int sx = dir ? (SQ - 1 - (s0 + si)) : (s0 + si);
    xs[si][t] = xln[sx * HD + t];
  }
  __syncthreads();
  const int k1 = t >> 8, j = t & 255;
  const int k2 = k1 + 2;
  const float* w1 = Wx + (size_t)(dir * 4 + k1) * HD * HHD + j;
  const float* w2 = Wx + (size_t)(dir * 4 + k2) * HD * HHD + j;
  float acc1[TS], acc2[TS];
  const float b1 = bg[(dir * 4 + k1) * HHD + j];
  const float b2 = bg[(dir * 4 + k2) * HHD + j];
#pragma unroll
  for (int si = 0; si < TS; ++si) { acc1[si] = b1; acc2[si] = b2; }
  for (int d = 0; d < HD; d += 4) {
    const float w1a = w1[(d + 0) * HHD], w1b = w1[(d + 1) * HHD];
    const float w1c = w1[(d + 2) * HHD], w1d = w1[(d + 3) * HHD];
    const float w2a = w2[(d + 0) * HHD], w2b = w2[(d + 1) * HHD];
    const float w2c = w2[(d + 2) * HHD], w2d = w2[(d + 3) * HHD];
#pragma unroll
    for (int si = 0; si < TS; ++si) {
      const float4 xv = *reinterpret_cast<const float4*>(&xs[si][d]);
      acc1[si] = fmaf(xv.x, w1a, acc1[si]);
      acc1[si] = fmaf(xv.y, w1b, acc1[si]);
      acc1[si] = fmaf(xv.z, w1c, acc1[si]);
      acc1[si] = fmaf(xv.w, w1d, acc1[si]);
      acc2[si] = fmaf(xv.x, w2a, acc2[si]);
      acc2[si] = fmaf(xv.y, w2b, acc2[si]);
      acc2[si] = fmaf(xv.z, w2c, acc2[si]);
      acc2[si] = fmaf(xv.w, w2d, acc2[si]);
    }
  }
  for (int si = 0; si < TS; ++si) {
    float* row = gx + ((size_t)(dir * SQ + s0 + si)) * 1024;
    row[t]       = acc1[si];
    row[t + 512] = acc2[si];
  }
}

__device__ __forceinline__ float tanh_fast(float x) {
  const float ax = fabsf(x);
  const float e  = __expf(-2.0f * ax);
  const float t  = __fdividef(1.0f - e, 1.0f + e);
  return copysignf(t, x);
}

// ---------------- Kernel R: sequential TLSTM recurrence — 2 WGs per direction.
// r3/r4/r6 all plateaued at ~5us/step with a 4-WG ring: the cost is the
// coherence-point visibility chain, so SHRINK THE RING. f16-packed weights
// (10-bit mantissa; weights +-0.1, h in [-1,1]; fp32 accumulate via v_dot2)
// halve storage -> 2 CUs per direction, ONE exchange partner.
// 10 blocks, active blockIdx&7<2: dir=blockIdx&7, wg=blockIdx>>3 (0..1).
// WG owns 128 cols. 512 thr: thread t -> col j=wg*128+(t&127), K-slice sk=t>>7
// (64 rows). Per thread 5 64-dots (4 gates + Wd) = 160 v_dot2.
// Weights: 128+32 packed u32 in VGPRs — single-level fully-unrolled loads only
// (r5 lesson: rolled loop -> scratch spill; verify VGPR_Count ~200-256).
// Exchange: own 128 cols as 64 h-pairs + 64 c-pairs (f16x2 payload) tagged
// (s+1)<<32, parity double-buffer, relaxed agent atomics. Waves 0-1 epilogue+
// publish; waves 2-3 poll partner; B1/B2 are LDS-only barriers.
__global__ __launch_bounds__(512, 2) void kR(const float* __restrict__ gx,
                                             const float* __restrict__ Wh,
                                             const float* __restrict__ Wd,
                                             const float* __restrict__ bd,
                                             const float* __restrict__ times,
                                             unsigned long long* __restrict__ comm,
                                             float* __restrict__ hfin) {
  const int slot = blockIdx.x & 7;
  if (slot >= 2) return;
  const int dir = slot;
  const int wg  = blockIdx.x >> 3;    // 0..1
  const int t   = threadIdx.x;        // 0..511
  const int tt  = t & 127;            // col within the owned 128
  const int sk  = t >> 7;             // K-slice 0..3 (wave-pair uniform)
  const int j   = wg * 128 + tt;      // owned global column
  const int lane = t & 63;

  // chunk layout: comm[((dir*2+w)*2 + parity)*128 + {p: h-pair, 64+p: c-pair}]
  unsigned long long* mybase = comm + (size_t)((dir * 2 + wg) * 2) * 128;
  const unsigned long long* pbase = comm + (size_t)((dir * 2 + (wg ^ 1)) * 2) * 128;

  // ---- persistent packed-f16 weights (single-level unrolled; const indices) ----
  h2 wh[128];   // [gate k][pair p]: rows (64*sk+2p, +1), col j
#pragma unroll
  for (int i = 0; i < 128; ++i) {
    const int k = i >> 5, p = i & 31;
    const int row = 64 * sk + 2 * p;
    const float w0 = Wh[((size_t)(dir * 4 + k) * HHD + row) * HHD + j];
    const float w1 = Wh[((size_t)(dir * 4 + k) * HHD + row + 1) * HHD + j];
    h2 v; v.x = (_Float16)w0; v.y = (_Float16)w1;
    wh[i] = v;
  }
  h2 wd[32];
#pragma unroll
  for (int i = 0; i < 32; ++i) {
    const int row = 64 * sk + 2 * i;
    const float w0 = Wd[(size_t)dir * HHD * HHD + (size_t)row * HHD + j];
    const float w1 = Wd[(size_t)dir * HHD * HHD + (size_t)(row + 1) * HHD + j];
    h2 v; v.x = (_Float16)w0; v.y = (_Float16)w1;
    wd[i] = v;
  }

  __shared__ unsigned h16[128];        // global pair -> packed f16 h (cols 2p,2p+1)
  __shared__ unsigned c16[128];
  __shared__ float pg[4][4][128];      // [gate][slice][col]
  __shared__ float pd[4][128];         // [slice][col]
  __shared__ float T_pre[SQ];

  for (int s = t; s < SQ; s += 512) {
    const int sidx = dir ? ((s == 0) ? 0 : (SQ - s)) : s;
    T_pre[s] = 1.0f / logf(times[sidx] + 2.7182818284590452354f);
  }
  if (t < 128) { h16[t] = 0u; c16[t] = 0u; }
  __syncthreads();                     // prologue only

  const float bdv = (t < 128) ? bd[dir * HHD + j] : 0.0f;
  const float* gxd = gx + (size_t)dir * SQ * 1024 + j;   // +k*256 per gate
  float g0 = 0, g1 = 0, g2 = 0, g3 = 0;
  if (t < 128) { g0 = gxd[0]; g1 = gxd[256]; g2 = gxd[512]; g3 = gxd[768]; }

  float h_my = 0.0f, c_my = 0.0f;      // fp32 master state for own column (epilogue thr)

  for (int s = 0; s < SQ; ++s) {
    // epilogue threads: prefetch next step's gx early
    float n0 = 0, n1 = 0, n2 = 0, n3 = 0;
    if (t < 128 && s + 1 < SQ) {
      const float* row = gxd + (size_t)(s + 1) * 1024;
      n0 = row[0]; n1 = row[256]; n2 = row[512]; n3 = row[768];
    }
    // ---- split-K dots: slice sk (pairs [32*sk, 32*sk+32)) for col j ----
    float a0 = 0, a1 = 0, a2 = 0, a3 = 0, ad = 0;
    const int base = 32 * sk;
#pragma unroll
    for (int i = 0; i < 32; ++i) {
      const h2 hp = u2h(h16[base + i]);     // broadcast across lanes (uniform addr)
      a0 = fdot2f(wh[i],       hp, a0);
      a1 = fdot2f(wh[32 + i],  hp, a1);
      a2 = fdot2f(wh[64 + i],  hp, a2);
      a3 = fdot2f(wh[96 + i],  hp, a3);
      const h2 cp = u2h(c16[base + i]);
      ad = fdot2f(wd[i], cp, ad);
    }
    pg[0][sk][tt] = a0;
    pg[1][sk][tt] = a1;
    pg[2][sk][tt] = a2;
    pg[3][sk][tt] = a3;
    pd[sk][tt]    = ad;
    BAR_LDS();                                         // B1
    if (t < 128) {
      // ---- epilogue: own col j ----
      const float s0 = pg[0][0][tt] + pg[0][1][tt] + pg[0][2][tt] + pg[0][3][tt];
      const float s1 = pg[1][0][tt] + pg[1][1][tt] + pg[1][2][tt] + pg[1][3][tt];
      const float s2 = pg[2][0][tt] + pg[2][1][tt] + pg[2][2][tt] + pg[2][3][tt];
      const float s3 = pg[3][0][tt] + pg[3][1][tt] + pg[3][2][tt] + pg[3][3][tt];
      const float sd = pd[0][tt] + pd[1][tt] + pd[2][tt] + pd[3][tt];
      const float iv  = __fdividef(1.0f, 1.0f + __expf(-(s0 + g0)));
      const float fv  = __fdividef(1.0f, 1.0f + __expf(-(s1 + g1)));
      const float ov  = __fdividef(1.0f, 1.0f + __expf(-(s2 + g2)));
      const float cgv = __fdividef(1.0f, 1.0f + __expf(-(s3 + g3)));
      const float c_st = tanh_fast(sd + bdv);
      const float T = T_pre[s];
      const float c_adj = c_my + (T - 1.0f) * c_st;
      const float ct = fv * c_adj + iv * cgv;
      const float hn = ov * tanh_fast(ct);
      c_my = ct;
      h_my = hn;
      // pack pairs via lane^1 shuffle (cols 2m,2m+1 are adjacent lanes)
      const float hn_o = __shfl(hn, lane ^ 1, 64);
      const float ct_o = __shfl(ct, lane ^ 1, 64);
      if ((lane & 1) == 0) {
        h2 hp; hp.x = (_Float16)hn; hp.y = (_Float16)hn_o;
        h2 cp; cp.x = (_Float16)ct; cp.y = (_Float16)ct_o;
        const unsigned hu = h2u(hp), cu = h2u(cp);
        const int pl = tt >> 1;                        // local pair 0..63
        h16[wg * 64 + pl] = hu;
        c16[wg * 64 + pl] = cu;
        unsigned long long* chunk = (unsigned long long*)mybase + (size_t)(s & 1) * 128;
        const unsigned long long tg = ((unsigned long long)(unsigned)(s + 1)) << 32;
        __hip_atomic_store(chunk + pl,      tg | hu, __ATOMIC_RELAXED, __HIP_MEMORY_SCOPE_AGENT);
        __hip_atomic_store(chunk + 64 + pl, tg | cu, __ATOMIC_RELAXED, __HIP_MEMORY_SCOPE_AGENT);
      }
    } else if (t < 256) {
      // ---- waves 2-3: poll partner's 128 tagged pairs ----
      const int p = t - 128;                           // 0..127
      const unsigned long long* chunk = pbase + (size_t)(s & 1) * 128;
      const unsigned tag = (unsigned)(s + 1);
      unsigned long long v;
      do {
        v = __hip_atomic_load(chunk + p, __ATOMIC_RELAXED, __HIP_MEMORY_SCOPE_AGENT);
      } while ((unsigned)(v >> 32) != tag);
      const unsigned payload = (unsigned)v;
      const int pg_idx = (wg ^ 1) * 64 + (p & 63);
      if (p < 64) h16[pg_idx] = payload;
      else        c16[pg_idx] = payload;
    }
    BAR_LDS();                                         // B2
    g0 = n0; g1 = n1; g2 = n2; g3 = n3;
  }
  if (t < 128) hfin[dir * HHD + j] = h_my;
}

// ---------------- Kernel D: logits = concat(hf,hb) @ W_cls + b_cls -> sigmoid -> out
__global__ __launch_bounds__(512) void kD(const float* __restrict__ hfin,
                                          const float* __restrict__ Wcls,
                                          const float* __restrict__ bcls,
                                          float* __restrict__ out) {
  __shared__ float red[8];
  const int t = threadIdx.x;          // 0..511
  float v = hfin[t] * Wcls[t];
#pragma unroll
  for (int o = 32; o >= 1; o >>= 1) v += __shfl_down(v, o, 64);
  if ((t & 63) == 0) red[t >> 6] = v;
  __syncthreads();
  if (t == 0) {
    float l = red[0] + red[1] + red[2] + red[3] + red[4] + red[5] + red[6] + red[7] + bcls[0];
    if (isnan(l) || isinf(l)) l = 0.0f;
    float p = 1.0f / (1.0f + expf(-l));
    if (isnan(p) || isinf(p)) p = 0.0f;
    out[0] = p;
  }
}

extern "C" void kernel_launch(void* const* d_in, const int* in_sizes, int n_in,
                              void* d_out, int out_size, void* d_ws, size_t ws_size,
                              hipStream_t stream) {
  const float* inputs    = (const float*)d_in[0];
  const float* times     = (const float*)d_in[1];
  const int*   nid       = (const int*)d_in[2];
  const int*   cid       = (const int*)d_in[3];
  const float* note_emb  = (const float*)d_in[4];
  const float* chunk_emb = (const float*)d_in[5];
  const float* W_comb    = (const float*)d_in[6];
  const float* b_comb    = (const float*)d_in[7];
  const float* ln_g      = (const float*)d_in[8];
  const float* ln_b      = (const float*)d_in[9];
  const float* Wx        = (const float*)d_in[10];
  const float* Wh        = (const float*)d_in[11];
  const float* bg        = (const float*)d_in[12];
  const float* Wd        = (const float*)d_in[13];
  const float* bd        = (const float*)d_in[14];
  const float* W_cls     = (const float*)d_in[15];
  const float* b_cls     = (const float*)d_in[16];

  float* ws   = (float*)d_ws;
  float* xln  = ws;                              // 4096*512    floats
  float* gx   = ws + (size_t)SQ * HD;            // 2*4096*1024 floats
  float* hfin = gx + (size_t)2 * SQ * 1024;      // 512 floats
  unsigned long long* comm = (unsigned long long*)(hfin + 512);  // 2*2*2*128 u64 = 8 KB

  kA<<<SQ / TS, 512, 0, stream>>>(inputs, nid, cid, note_emb, chunk_emb, W_comb, b_comb, xln);
  kB<<<SQ, 256, 0, stream>>>(xln, ln_g, ln_b);
  kC<<<dim3(SQ / TS, 2), 512, 0, stream>>>(xln, Wx, bg, gx);
  kR<<<10, 512, 0, stream>>>(gx, Wh, Wd, bd, times, comm, hfin);
  kD<<<1, 512, 0, stream>>>(hfin, W_cls, b_cls, (float*)d_out);
}